// Round 5
// baseline (179.738 us; speedup 1.0000x reference)
//
#include <hip/hip_runtime.h>
#include <math.h>

// Problem constants
#define TT 16384   // tokens
#define HH 2048    // hidden
#define EE 64      // experts
#define KK 8       // top_k

#define TB 32          // tokens per block
#define HC 64          // h per chunk
#define NCH (HH / HC)  // 32 chunks
#define RS 66          // reduction row stride (floats)
#define TOPC 12        // fp32 candidate count for fixup
#define MARGIN 4e-6f   // selection-score gap below which we fp64-verify

// Output layout (flat float32):
// probs [TT][KK] | indices [TT][KK] | map [TT][EE] | aux scalar
#define IDX_OFF ((size_t)TT * KK)
#define MAP_OFF ((size_t)2 * TT * KK)
#define AUX_OFF ((size_t)2 * TT * KK + (size_t)TT * EE)

// expert -> storage slot permutation inside a W row (spreads stride-8 reads
// across banks: slot = (e & ~7) | ((e + (e>>3)) & 7), bijective per 8-block)
#define WPERM(e) (((e) & ~7) | (((e) + ((e) >> 3)) & 7))

// reduction helpers as macros (NO lambdas -- R4's acc spilled via lambda capture)
#define WRITE_RED(BUF)                                                          \
  do {                                                                          \
    _Pragma("unroll") for (int i_ = 0; i_ < 8; ++i_) {                          \
      float* row_ = (BUF) + (tg + 4 * i_) * RS + 8 * eg;                        \
      *reinterpret_cast<float4*>(row_) =                                        \
          make_float4(acc[i_][0], acc[i_][1], acc[i_][2], acc[i_][3]);          \
      *reinterpret_cast<float4*>(row_ + 4) =                                    \
          make_float4(acc[i_][4], acc[i_][5], acc[i_][6], acc[i_][7]);          \
    }                                                                           \
  } while (0)

#define ADD_RED(BUF)                                                            \
  do {                                                                          \
    _Pragma("unroll") for (int i_ = 0; i_ < 8; ++i_) {                          \
      const float* row_ = (BUF) + (tg + 4 * i_) * RS + 8 * eg;                  \
      float4 lo_ = *reinterpret_cast<const float4*>(row_);                      \
      float4 hi_ = *reinterpret_cast<const float4*>(row_ + 4);                  \
      acc[i_][0] += lo_.x; acc[i_][1] += lo_.y;                                 \
      acc[i_][2] += lo_.z; acc[i_][3] += lo_.w;                                 \
      acc[i_][4] += hi_.x; acc[i_][5] += hi_.y;                                 \
      acc[i_][6] += hi_.z; acc[i_][7] += hi_.w;                                 \
    }                                                                           \
  } while (0)

__global__ __launch_bounds__(256, 2)
void router_kernel(const float* __restrict__ hidden,
                   const float* __restrict__ gate_w,
                   const float* __restrict__ bias,
                   float* __restrict__ out)
{
    // 4 reduction buffers of [32][66] f32 = 8448 floats (33792 B).
    // Staging (stH 528 + stW 1040 float4 = 6272 floats) overlays the front.
    __shared__ float smem[4 * TB * RS];
    float4* stH = reinterpret_cast<float4*>(smem);   // [16][33] float4
    float4* stW = stH + 16 * 33;                     // [16][65] float4
    float* B0 = smem;
    float* B1 = smem + 1 * TB * RS;
    float* B2 = smem + 2 * TB * RS;
    float* B3 = smem + 3 * TB * RS;

    const int tid = threadIdx.x;
    const int s   = tid >> 5;          // h-split 0..7
    const int tg  = (tid >> 3) & 3;    // token group: tokens tg + 4i, i=0..7
    const int eg  = tid & 7;           // expert group: experts 8eg..8eg+7
    const int tok0 = blockIdx.x * TB;

    // staging coords (R3's validated pattern)
    const int f4s = tid & 15;
    const int tw  = tid >> 4;          // 0..15

    const float* hbase = hidden + (size_t)(tok0 + tw) * HH + 4 * f4s;
    const float* wbase = gate_w + (size_t)tw * HH + 4 * f4s;

    float acc[8][8];
    #pragma unroll
    for (int i = 0; i < 8; ++i)
        #pragma unroll
        for (int j = 0; j < 8; ++j) acc[i][j] = 0.0f;

    // prologue: load chunk 0
    float4 hv[2], wv[4];
    #pragma unroll
    for (int k = 0; k < 2; ++k)
        hv[k] = *reinterpret_cast<const float4*>(hbase + (size_t)16 * k * HH);
    #pragma unroll
    for (int k = 0; k < 4; ++k)
        wv[k] = *reinterpret_cast<const float4*>(wbase + (size_t)16 * k * HH);

    for (int c = 0; c < NCH; ++c) {
        __syncthreads();   // previous chunk's compute done
        stH[f4s * 33 + tw]      = hv[0];
        stH[f4s * 33 + tw + 16] = hv[1];
        #pragma unroll
        for (int k = 0; k < 4; ++k)
            stW[f4s * 65 + WPERM(tw + 16 * k)] = wv[k];
        __syncthreads();   // staging visible

        if (c + 1 < NCH) {
            #pragma unroll
            for (int k = 0; k < 2; ++k)
                hv[k] = *reinterpret_cast<const float4*>(
                    hbase + (size_t)16 * k * HH + (c + 1) * HC);
            #pragma unroll
            for (int k = 0; k < 4; ++k)
                wv[k] = *reinterpret_cast<const float4*>(
                    wbase + (size_t)16 * k * HH + (c + 1) * HC);
        }

        // compute: split s covers h-quads {2s, 2s+1}; 8 tok x 8 exp fp32 tile
        #pragma unroll
        for (int u = 0; u < 2; ++u) {
            const int f4r = 2 * s + u;
            float4 ha[8];
            #pragma unroll
            for (int i = 0; i < 8; ++i)
                ha[i] = stH[f4r * 33 + tg + 4 * i];
            #pragma unroll
            for (int jh = 0; jh < 2; ++jh) {
                float4 wb[4];
                #pragma unroll
                for (int j = 0; j < 4; ++j)
                    wb[j] = stW[f4r * 65 + 8 * eg + ((4 * jh + j + eg) & 7)];
                #pragma unroll
                for (int i = 0; i < 8; ++i) {
                    #pragma unroll
                    for (int j = 0; j < 4; ++j) {
                        acc[i][4*jh+j] = fmaf(ha[i].x, wb[j].x, acc[i][4*jh+j]);
                        acc[i][4*jh+j] = fmaf(ha[i].y, wb[j].y, acc[i][4*jh+j]);
                        acc[i][4*jh+j] = fmaf(ha[i].z, wb[j].z, acc[i][4*jh+j]);
                        acc[i][4*jh+j] = fmaf(ha[i].w, wb[j].w, acc[i][4*jh+j]);
                    }
                }
            }
        }
    }

    // ---- reduce 8 h-split partials (fixed tree, deterministic) ----
    __syncthreads();
    if (s == 4) WRITE_RED(B0);
    if (s == 5) WRITE_RED(B1);
    if (s == 6) WRITE_RED(B2);
    if (s == 7) WRITE_RED(B3);
    __syncthreads();
    if (s == 0) ADD_RED(B0);
    if (s == 1) ADD_RED(B1);
    if (s == 2) ADD_RED(B2);
    if (s == 3) ADD_RED(B3);
    __syncthreads();
    if (s == 2) WRITE_RED(B0);
    if (s == 3) WRITE_RED(B1);
    __syncthreads();
    if (s == 0) ADD_RED(B0);
    if (s == 1) ADD_RED(B1);
    __syncthreads();
    if (s == 1) WRITE_RED(B0);
    __syncthreads();
    if (s == 0) { ADD_RED(B0); WRITE_RED(B1); }
    __syncthreads();

    // ---- epilogue: 8 lanes per token; logits in B1[t][e] ----
    const int t = tid >> 3;
    const int q = tid & 7;    // lane owns experts q + 8i
    const int tok = tok0 + t;

    float lv[8];
    #pragma unroll
    for (int i = 0; i < 8; ++i) lv[i] = B1[t * RS + q + 8 * i];

    float mx = lv[0];
    #pragma unroll
    for (int i = 1; i < 8; ++i) mx = fmaxf(mx, lv[i]);
    #pragma unroll
    for (int sh = 1; sh < 8; sh <<= 1) mx = fmaxf(mx, __shfl_xor(mx, sh, 64));

    float ex[8], psum = 0.0f;
    #pragma unroll
    for (int i = 0; i < 8; ++i) { ex[i] = expf(lv[i] - mx); psum += ex[i]; }
    #pragma unroll
    for (int sh = 1; sh < 8; sh <<= 1) psum += __shfl_xor(psum, sh, 64);
    const float inv = 1.0f / psum;

    float pr[8], selv[8];
    #pragma unroll
    for (int i = 0; i < 8; ++i) {
        pr[i]   = ex[i] * inv;
        selv[i] = pr[i] + bias[q + 8 * i];
    }

    // top-12 candidates (fp32), strict-> + lowest-index tie-break
    float ws[TOPC], wp[TOPC];
    int   wi[TOPC];
    #pragma unroll
    for (int k = 0; k < TOPC; ++k) {
        float bs = selv[0], bp = pr[0];
        int bi = q;
        #pragma unroll
        for (int i = 1; i < 8; ++i)
            if (selv[i] > bs) { bs = selv[i]; bp = pr[i]; bi = q + 8 * i; }
        #pragma unroll
        for (int sh = 1; sh < 8; sh <<= 1) {
            float os = __shfl_xor(bs, sh, 64);
            float op = __shfl_xor(bp, sh, 64);
            int   ob = __shfl_xor(bi, sh, 64);
            if (os > bs || (os == bs && ob < bi)) { bs = os; bp = op; bi = ob; }
        }
        ws[k] = bs; wp[k] = bp; wi[k] = bi;
        #pragma unroll
        for (int i = 0; i < 8; ++i)
            if (((bi >> 3) == i) && ((bi & 7) == q)) selv[i] = -INFINITY;
    }

    // flag: any gap among ranks 1..9 too small to trust fp32 ranking
    bool flag = false;
    #pragma unroll
    for (int k = 0; k < 8; ++k)
        flag = flag || (ws[k] - ws[k + 1] < MARGIN);

    if (flag) {
        // fp64 re-dot of the 12 candidates (group-uniform branch; 8 lanes)
        const float* hrow = hidden + (size_t)tok * HH;
        const float* wr[TOPC];
        #pragma unroll
        for (int k = 0; k < TOPC; ++k) wr[k] = gate_w + (size_t)wi[k] * HH;

        double l64[TOPC];
        #pragma unroll
        for (int k = 0; k < TOPC; ++k) l64[k] = 0.0;

        for (int m = 0; m < 64; ++m) {
            float4 h4 = *reinterpret_cast<const float4*>(hrow + m * 32 + 4 * q);
            double h0 = h4.x, h1 = h4.y, h2 = h4.z, h3 = h4.w;
            #pragma unroll
            for (int k = 0; k < TOPC; ++k) {
                float4 w4 = *reinterpret_cast<const float4*>(wr[k] + m * 32 + 4 * q);
                l64[k] = fma(h0, (double)w4.x, l64[k]);
                l64[k] = fma(h1, (double)w4.y, l64[k]);
                l64[k] = fma(h2, (double)w4.z, l64[k]);
                l64[k] = fma(h3, (double)w4.w, l64[k]);
            }
        }
        #pragma unroll
        for (int k = 0; k < TOPC; ++k)
            #pragma unroll
            for (int sh = 1; sh < 8; sh <<= 1)
                l64[k] += __shfl_xor(l64[k], sh, 64);

        // selection scores; monotone-exact ranking (bias exact, Z/m scale shared)
        double s64[TOPC];
        #pragma unroll
        for (int k = 0; k < TOPC; ++k)
            s64[k] = exp(l64[k] - (double)mx) * (double)inv + (double)bias[wi[k]];

        // selection sort: order first 8 by (score desc, idx asc); static indices
        #pragma unroll
        for (int a = 0; a < 8; ++a) {
            #pragma unroll
            for (int b = a + 1; b < TOPC; ++b) {
                bool sw = (s64[b] > s64[a]) ||
                          (s64[b] == s64[a] && wi[b] < wi[a]);
                if (sw) {
                    double td = s64[a]; s64[a] = s64[b]; s64[b] = td;
                    int    ti = wi[a];  wi[a]  = wi[b];  wi[b]  = ti;
                    float  tp = wp[a];  wp[a]  = wp[b];  wp[b]  = tp;
                }
            }
        }
    }

    // ---- common write-out (wi/wp[0..7] hold the final ranking) ----
    int oi = wi[0];
    float opf = wp[0];
    #pragma unroll
    for (int k = 1; k < 8; ++k)
        if (q == k) { oi = wi[k]; opf = wp[k]; }

    float ps = 0.0f;
    #pragma unroll
    for (int k = 0; k < 8; ++k) ps += wp[k];
    const float rinv = 1.0f / (ps + 1e-9f);

    out[(size_t)tok * KK + q]           = opf * rinv;
    out[IDX_OFF + (size_t)tok * KK + q] = (float)oi;

    unsigned long long mk = 0ull;
    #pragma unroll
    for (int k = 0; k < 8; ++k) mk |= (1ull << wi[k]);

    {
        float4 a, b;
        a.x = ((mk >> (8 * q + 0)) & 1ull) ? 1.0f : 0.0f;
        a.y = ((mk >> (8 * q + 1)) & 1ull) ? 1.0f : 0.0f;
        a.z = ((mk >> (8 * q + 2)) & 1ull) ? 1.0f : 0.0f;
        a.w = ((mk >> (8 * q + 3)) & 1ull) ? 1.0f : 0.0f;
        b.x = ((mk >> (8 * q + 4)) & 1ull) ? 1.0f : 0.0f;
        b.y = ((mk >> (8 * q + 5)) & 1ull) ? 1.0f : 0.0f;
        b.z = ((mk >> (8 * q + 6)) & 1ull) ? 1.0f : 0.0f;
        b.w = ((mk >> (8 * q + 7)) & 1ull) ? 1.0f : 0.0f;
        float* mo = out + MAP_OFF + (size_t)tok * EE + 8 * q;
        reinterpret_cast<float4*>(mo)[0] = a;
        reinterpret_cast<float4*>(mo)[1] = b;
    }

    if (blockIdx.x == 0 && tid == 0) out[AUX_OFF] = 0.0f;
}

extern "C" void kernel_launch(void* const* d_in, const int* in_sizes, int n_in,
                              void* d_out, int out_size, void* d_ws, size_t ws_size,
                              hipStream_t stream) {
    const float* hidden = (const float*)d_in[0];  // [16384, 2048] f32
    const float* gate_w = (const float*)d_in[1];  // [64, 2048] f32
    const float* bias   = (const float*)d_in[2];  // [64] f32
    float* out = (float*)d_out;

    router_kernel<<<TT / TB, 256, 0, stream>>>(hidden, gate_w, bias, out);
}

// Round 6
// 148.073 us; speedup vs baseline: 1.2138x; 1.2138x over previous
//
#include <hip/hip_runtime.h>
#include <math.h>

// Problem constants
#define TT 16384   // tokens
#define HH 2048    // hidden
#define EE 64      // experts
#define KK 8       // top_k

#define TB 32          // tokens per block
#define HC 64          // h per chunk
#define NCH (HH / HC)  // 32 chunks
#define RS 66          // reduction row stride (floats)
#define TOPC 10        // fp32 candidate count for fixup
#define MARGIN 4e-6f   // selection-score gap below which we fp64-verify

// Output layout (flat float32):
// probs [TT][KK] | indices [TT][KK] | map [TT][EE] | aux scalar
#define IDX_OFF ((size_t)TT * KK)
#define MAP_OFF ((size_t)2 * TT * KK)
#define AUX_OFF ((size_t)2 * TT * KK + (size_t)TT * EE)

// W storage slot within a row: expert e -> 8*(e&7) + (e>>3)  (bijective 0..63).
// Thread eg reads its experts 8eg..8eg+7 at slots 8j+eg  -> banks (f4r+eg)&7,
// 8 distinct across lanes => conflict-free broadcast reads.
#define WSLOT(e) (8 * ((e) & 7) + ((e) >> 3))

// Reduction macros (no lambdas - R4 spilled via lambda capture of acc)
#define WRITE_RED(BUF)                                                         \
  do {                                                                         \
    _Pragma("unroll") for (int i_ = 0; i_ < 4; ++i_) {                         \
      float* row_ = (BUF) + (tg + 8 * i_) * RS + 8 * eg;                       \
      *reinterpret_cast<float4*>(row_) =                                       \
          make_float4(acc[i_][0], acc[i_][1], acc[i_][2], acc[i_][3]);         \
      *reinterpret_cast<float4*>(row_ + 4) =                                   \
          make_float4(acc[i_][4], acc[i_][5], acc[i_][6], acc[i_][7]);         \
    }                                                                          \
  } while (0)

#define ADD_RED(BUF)                                                           \
  do {                                                                         \
    _Pragma("unroll") for (int i_ = 0; i_ < 4; ++i_) {                         \
      const float* row_ = (BUF) + (tg + 8 * i_) * RS + 8 * eg;                 \
      float4 lo_ = *reinterpret_cast<const float4*>(row_);                     \
      float4 hi_ = *reinterpret_cast<const float4*>(row_ + 4);                 \
      acc[i_][0] += lo_.x; acc[i_][1] += lo_.y;                                \
      acc[i_][2] += lo_.z; acc[i_][3] += lo_.w;                                \
      acc[i_][4] += hi_.x; acc[i_][5] += hi_.y;                                \
      acc[i_][6] += hi_.z; acc[i_][7] += hi_.w;                                \
    }                                                                          \
  } while (0)

__global__ __launch_bounds__(512, 2)
void router_kernel(const float* __restrict__ hidden,
                   const float* __restrict__ gate_w,
                   const float* __restrict__ bias,
                   float* __restrict__ out)
{
    // 4 reduction buffers [32][66] f32 = 33792 B; staging overlays the front:
    // stH [16][33] float4 (8448 B) | stW [16][65] float4 (16640 B) = 25088 B.
    __shared__ float smem[4 * TB * RS];
    float4* stH = reinterpret_cast<float4*>(smem);   // [16][33]
    float4* stW = stH + 16 * 33;                     // [16][65]
    float* B0 = smem;
    float* B1 = smem + 1 * TB * RS;
    float* B2 = smem + 2 * TB * RS;
    float* B3 = smem + 3 * TB * RS;

    const int tid = threadIdx.x;
    const int s   = tid >> 6;          // h-split 0..7 (one wave per split)
    const int r   = tid & 63;
    const int tg  = r >> 3;            // tokens tg + 8i, i=0..3
    const int eg  = r & 7;             // experts 8eg..8eg+7
    const int tok0 = blockIdx.x * TB;

    // staging coords
    const int f4s = tid & 15;          // h float4 slot 0..15
    const int tw  = tid >> 4;          // 0..31

    const float* hbase = hidden + (size_t)(tok0 + tw) * HH + 4 * f4s;
    const float* wbase = gate_w + (size_t)tw * HH + 4 * f4s;

    float acc[4][8];
    #pragma unroll
    for (int i = 0; i < 4; ++i)
        #pragma unroll
        for (int j = 0; j < 8; ++j) acc[i][j] = 0.0f;

    // prologue: load chunk 0 (3 float4s/thread)
    float4 hv, wv0, wv1;
    hv  = *reinterpret_cast<const float4*>(hbase);
    wv0 = *reinterpret_cast<const float4*>(wbase);
    wv1 = *reinterpret_cast<const float4*>(wbase + (size_t)32 * HH);

    for (int c = 0; c < NCH; ++c) {
        __syncthreads();   // previous chunk's compute done
        stH[f4s * 33 + tw]               = hv;
        stW[f4s * 65 + WSLOT(tw)]        = wv0;
        stW[f4s * 65 + WSLOT(tw + 32)]   = wv1;
        __syncthreads();   // staging visible

        if (c + 1 < NCH) {
            hv  = *reinterpret_cast<const float4*>(hbase + (c + 1) * HC);
            wv0 = *reinterpret_cast<const float4*>(wbase + (c + 1) * HC);
            wv1 = *reinterpret_cast<const float4*>(
                wbase + (size_t)32 * HH + (c + 1) * HC);
        }

        // compute: split s covers f4-rows {2s, 2s+1}; 4 tok x 8 exp tile
        #pragma unroll
        for (int u = 0; u < 2; ++u) {
            const int f4r = 2 * s + u;
            float4 ha[4];
            #pragma unroll
            for (int i = 0; i < 4; ++i)
                ha[i] = stH[f4r * 33 + tg + 8 * i];

            // experts in two groups of 4 to cap live registers
            #pragma unroll
            for (int g = 0; g < 2; ++g) {
                float4 wb[4];
                #pragma unroll
                for (int j = 0; j < 4; ++j)
                    wb[j] = stW[f4r * 65 + 8 * (4 * g + j) + eg];
                #pragma unroll
                for (int i = 0; i < 4; ++i)
                    #pragma unroll
                    for (int j = 0; j < 4; ++j) {
                        float a_ = acc[i][4 * g + j];
                        a_ = fmaf(ha[i].x, wb[j].x, a_);
                        a_ = fmaf(ha[i].y, wb[j].y, a_);
                        a_ = fmaf(ha[i].z, wb[j].z, a_);
                        a_ = fmaf(ha[i].w, wb[j].w, a_);
                        acc[i][4 * g + j] = a_;
                    }
            }
        }
    }

    // ---- reduce 8 h-split partials (fixed deterministic tree) ----
    __syncthreads();
    if (s == 4) WRITE_RED(B0);
    if (s == 5) WRITE_RED(B1);
    if (s == 6) WRITE_RED(B2);
    if (s == 7) WRITE_RED(B3);
    __syncthreads();
    if (s == 0) ADD_RED(B0);
    if (s == 1) ADD_RED(B1);
    if (s == 2) ADD_RED(B2);
    if (s == 3) ADD_RED(B3);
    __syncthreads();
    if (s == 2) WRITE_RED(B0);
    if (s == 3) WRITE_RED(B1);
    __syncthreads();
    if (s == 0) ADD_RED(B0);
    if (s == 1) ADD_RED(B1);
    __syncthreads();
    if (s == 1) WRITE_RED(B0);
    __syncthreads();
    if (s == 0) { ADD_RED(B0); WRITE_RED(B1); }
    __syncthreads();

    // ---- epilogue: 16 lanes per token; logits in B1[t][e] ----
    const int t = tid >> 4;   // 0..31
    const int q = tid & 15;   // lane owns experts q + 16i, i=0..3
    const int tok = tok0 + t;

    float lv[4];
    #pragma unroll
    for (int i = 0; i < 4; ++i) lv[i] = B1[t * RS + q + 16 * i];

    float mx = lv[0];
    #pragma unroll
    for (int i = 1; i < 4; ++i) mx = fmaxf(mx, lv[i]);
    #pragma unroll
    for (int sh = 1; sh < 16; sh <<= 1) mx = fmaxf(mx, __shfl_xor(mx, sh, 64));

    float ex[4], psum = 0.0f;
    #pragma unroll
    for (int i = 0; i < 4; ++i) { ex[i] = expf(lv[i] - mx); psum += ex[i]; }
    #pragma unroll
    for (int sh = 1; sh < 16; sh <<= 1) psum += __shfl_xor(psum, sh, 64);
    const float inv = 1.0f / psum;

    float pr[4], selv[4];
    #pragma unroll
    for (int i = 0; i < 4; ++i) {
        pr[i]   = ex[i] * inv;
        selv[i] = pr[i] + bias[q + 16 * i];
    }

    // top-10 candidates (fp32), strict-> with lowest-index tie-break
    float ws[TOPC], wp[TOPC];
    int   wi[TOPC];
    #pragma unroll
    for (int k = 0; k < TOPC; ++k) {
        float bs = selv[0], bp = pr[0];
        int bi = q;
        #pragma unroll
        for (int i = 1; i < 4; ++i)
            if (selv[i] > bs) { bs = selv[i]; bp = pr[i]; bi = q + 16 * i; }
        #pragma unroll
        for (int sh = 1; sh < 16; sh <<= 1) {
            float os = __shfl_xor(bs, sh, 64);
            float op = __shfl_xor(bp, sh, 64);
            int   ob = __shfl_xor(bi, sh, 64);
            if (os > bs || (os == bs && ob < bi)) { bs = os; bp = op; bi = ob; }
        }
        ws[k] = bs; wp[k] = bp; wi[k] = bi;
        #pragma unroll
        for (int i = 0; i < 4; ++i)
            if (q + 16 * i == bi) selv[i] = -INFINITY;
    }

    // flag: any adjacent gap among ranks 1..9 too small to trust fp32
    bool flag = false;
    #pragma unroll
    for (int k = 0; k < 8; ++k)
        flag = flag || (ws[k] - ws[k + 1] < MARGIN);

    if (flag) {   // uniform across the 16-lane token group
        const float* hrow = hidden + (size_t)tok * HH;
        double l64[TOPC];
        #pragma unroll
        for (int k = 0; k < TOPC; ++k) l64[k] = 0.0;

        for (int m = 0; m < 32; ++m) {
            float4 h4 = *reinterpret_cast<const float4*>(hrow + m * 64 + 4 * q);
            double h0 = h4.x, h1 = h4.y, h2 = h4.z, h3 = h4.w;
            #pragma unroll
            for (int k = 0; k < TOPC; ++k) {
                float4 w4 = *reinterpret_cast<const float4*>(
                    gate_w + (size_t)wi[k] * HH + m * 64 + 4 * q);
                l64[k] = fma(h0, (double)w4.x, l64[k]);
                l64[k] = fma(h1, (double)w4.y, l64[k]);
                l64[k] = fma(h2, (double)w4.z, l64[k]);
                l64[k] = fma(h3, (double)w4.w, l64[k]);
            }
        }
        #pragma unroll
        for (int k = 0; k < TOPC; ++k)
            #pragma unroll
            for (int sh = 1; sh < 16; sh <<= 1)
                l64[k] += __shfl_xor(l64[k], sh, 64);

        // exact-rank selection scores (common positive rescale; bias exact)
        double s64[TOPC];
        #pragma unroll
        for (int k = 0; k < TOPC; ++k)
            s64[k] = exp(l64[k] - (double)mx) * (double)inv +
                     (double)bias[wi[k]];

        // order first 8 by (score desc, idx asc) - static indices only
        #pragma unroll
        for (int a = 0; a < 8; ++a) {
            #pragma unroll
            for (int b = a + 1; b < TOPC; ++b) {
                bool sw = (s64[b] > s64[a]) ||
                          (s64[b] == s64[a] && wi[b] < wi[a]);
                if (sw) {
                    double td = s64[a]; s64[a] = s64[b]; s64[b] = td;
                    int    ti = wi[a];  wi[a]  = wi[b];  wi[b]  = ti;
                    float  tp = wp[a];  wp[a]  = wp[b];  wp[b]  = tp;
                }
            }
        }
    }

    // ---- common write-out (wi/wp[0..7] final) ----
    int oi = wi[0];
    float opf = wp[0];
    #pragma unroll
    for (int k = 1; k < 8; ++k)
        if (q == k) { oi = wi[k]; opf = wp[k]; }

    float ps = 0.0f;
    #pragma unroll
    for (int k = 0; k < 8; ++k) ps += wp[k];
    const float rinv = 1.0f / (ps + 1e-9f);

    if (q < KK) {
        out[(size_t)tok * KK + q]           = opf * rinv;
        out[IDX_OFF + (size_t)tok * KK + q] = (float)oi;
    }

    unsigned long long mk = 0ull;
    #pragma unroll
    for (int k = 0; k < 8; ++k) mk |= (1ull << wi[k]);

    {
        float4 a;
        a.x = ((mk >> (4 * q + 0)) & 1ull) ? 1.0f : 0.0f;
        a.y = ((mk >> (4 * q + 1)) & 1ull) ? 1.0f : 0.0f;
        a.z = ((mk >> (4 * q + 2)) & 1ull) ? 1.0f : 0.0f;
        a.w = ((mk >> (4 * q + 3)) & 1ull) ? 1.0f : 0.0f;
        reinterpret_cast<float4*>(out + MAP_OFF + (size_t)tok * EE + 4 * q)[0] = a;
    }

    if (blockIdx.x == 0 && tid == 0) out[AUX_OFF] = 0.0f;
}

extern "C" void kernel_launch(void* const* d_in, const int* in_sizes, int n_in,
                              void* d_out, int out_size, void* d_ws, size_t ws_size,
                              hipStream_t stream) {
    const float* hidden = (const float*)d_in[0];  // [16384, 2048] f32
    const float* gate_w = (const float*)d_in[1];  // [64, 2048] f32
    const float* bias   = (const float*)d_in[2];  // [64] f32
    float* out = (float*)d_out;

    router_kernel<<<TT / TB, 512, 0, stream>>>(hidden, gate_w, bias, out);
}